// Round 17
// baseline (201.518 us; speedup 1.0000x reference)
//
#include <hip/hip_runtime.h>
#include <hip/hip_bf16.h>

constexpr int NROW = 8192;
constexpr int INF  = 256;
constexpr int OUTF = 128;
constexpr int KSPLIT = 8;
constexpr int KCHUNK = NROW / KSPLIT; // 1024
constexpr int NIT    = KCHUNK / 64;   // 16 k-iterations per block
#define LOG2E 1.4426950408889634f

typedef __bf16 bf16x8 __attribute__((ext_vector_type(8)));
typedef float  f32x4  __attribute__((ext_vector_type(4)));
typedef int    i32x4  __attribute__((ext_vector_type(4)));
typedef unsigned long long u64;

// ---------------------------------------------------------------------------
// k1: h = x@W (f32 accum); f1 = (h@a1)*log2e, f2 = (h@a2)*log2e; ht = h^T bf16
// grid: NROW/32 blocks, 256 threads
// ---------------------------------------------------------------------------
__global__ __launch_bounds__(256) void k1(const float* __restrict__ x,
                                          const float* __restrict__ W,
                                          const float* __restrict__ a,
                                          __bf16* __restrict__ ht,
                                          float* __restrict__ f1,
                                          float* __restrict__ f2) {
  __shared__ float xs[32][INF];   // 32 KB
  __shared__ float hs[32][OUTF];  // 16 KB
  const int t  = threadIdx.x;
  const int i0 = blockIdx.x * 32;

  const f32x4* xsrc = reinterpret_cast<const f32x4*>(x + (size_t)i0 * INF);
  f32x4* xdst = reinterpret_cast<f32x4*>(&xs[0][0]);
  #pragma unroll
  for (int u = 0; u < (32 * INF / 4) / 256; ++u)
    xdst[u * 256 + t] = xsrc[u * 256 + t];
  __syncthreads();

  const int c  = t & 127;
  const int rg = t >> 7;  // 0/1 -> rows rg*16 .. rg*16+15
  float acc[16];
  #pragma unroll
  for (int r = 0; r < 16; ++r) acc[r] = 0.f;
  for (int k = 0; k < INF; ++k) {
    float wv = W[k * OUTF + c];
    #pragma unroll
    for (int r = 0; r < 16; ++r) acc[r] += xs[rg * 16 + r][k] * wv;
  }
  #pragma unroll
  for (int r = 0; r < 16; ++r) hs[rg * 16 + r][c] = acc[r];
  __syncthreads();

  const int wv = t >> 6, lane = t & 63;
  for (int r = wv; r < 32; r += 4) {
    float h0 = hs[r][lane * 2], h1 = hs[r][lane * 2 + 1];
    float s1 = h0 * a[lane * 2] + h1 * a[lane * 2 + 1];
    float s2 = h0 * a[OUTF + lane * 2] + h1 * a[OUTF + lane * 2 + 1];
    #pragma unroll
    for (int off = 32; off; off >>= 1) {
      s1 += __shfl_down(s1, off);
      s2 += __shfl_down(s2, off);
    }
    if (lane == 0) { f1[i0 + r] = s1 * LOG2E; f2[i0 + r] = s2 * LOG2E; }
  }

  const int col = t >> 1, seg = t & 1;
  bf16x8 v0, v1;
  #pragma unroll
  for (int r = 0; r < 8; ++r) v0[r] = (__bf16)hs[seg * 16 + r][col];
  #pragma unroll
  for (int r = 0; r < 8; ++r) v1[r] = (__bf16)hs[seg * 16 + 8 + r][col];
  __bf16* hdst = ht + (size_t)col * NROW + i0 + seg * 16;
  *reinterpret_cast<bf16x8*>(hdst)     = v0;
  *reinterpret_cast<bf16x8*>(hdst + 8) = v1;
}

// ---------------------------------------------------------------------------
// katt2: one row per block, 8192 blocks. Phase 1 pure read (f2 kept in
// registers); phase 1.5 emits the packed adjacency bitmask + row sum; phase
// 2 pure register-fed write stream. 524 MB @ ~5.7 TB/s (r15) ~= copy ceiling.
// grid: NROW blocks, 256 threads
// ---------------------------------------------------------------------------
__global__ __launch_bounds__(256) void katt2(const int* __restrict__ adj,
                                             const float* __restrict__ f1,
                                             const float* __restrict__ f2,
                                             u64* __restrict__ mask,
                                             float* __restrict__ s,
                                             float* __restrict__ att) {
  const int i = blockIdx.x;
  const int t = threadIdx.x;
  const int lane = t & 63, wv = t >> 6;
  const float f1i = f1[i];
  const i32x4* arow = reinterpret_cast<const i32x4*>(adj + (size_t)i * NROW);
  const f32x4* f2v  = reinterpret_cast<const f32x4*>(f2);
  u64* mrow = mask + (size_t)i * 128;

  unsigned mynibs = 0;
  float acc = 0.f;
  f32x4 fv[8];
  #pragma unroll
  for (int it = 0; it < 8; ++it) {
    i32x4 av = __builtin_nontemporal_load(arow + it * 256 + t);
    fv[it] = f2v[it * 256 + t];
    unsigned nib = (av[0] > 0) | ((av[1] > 0) << 1) | ((av[2] > 0) << 2) |
                   ((av[3] > 0) << 3);
    mynibs |= nib << (it * 4);
    #pragma unroll
    for (int b = 0; b < 4; ++b) {
      float e = f1i + fv[it][b];
      e = e > 0.f ? e : 0.01f * e;
      acc += ((nib >> b) & 1u) ? __builtin_exp2f(e) : 0.f;
    }
  }

  #pragma unroll
  for (int it = 0; it < 8; ++it) {
    u64 m = (u64)((mynibs >> (it * 4)) & 0xFu) << (4 * (lane & 15));
    #pragma unroll
    for (int d = 1; d < 16; d <<= 1) m |= __shfl_xor(m, d);
    if ((lane & 15) == 0) mrow[it * 16 + (t >> 4)] = m;
  }
  #pragma unroll
  for (int off = 32; off; off >>= 1) acc += __shfl_down(acc, off);
  __shared__ float red[4];
  if (lane == 0) red[wv] = acc;
  __syncthreads();
  const float srow = red[0] + red[1] + red[2] + red[3];
  if (t == 0) s[i] = srow;
  const float inv_s = 1.0f / srow;

  f32x4* adst = reinterpret_cast<f32x4*>(att + (size_t)i * NROW);
  #pragma unroll
  for (int it = 0; it < 8; ++it) {
    const unsigned nib = (mynibs >> (it * 4)) & 0xFu;
    f32x4 o;
    #pragma unroll
    for (int b = 0; b < 4; ++b) {
      float e = f1i + fv[it][b];
      e = e > 0.f ? e : 0.01f * e;
      o[b] = ((nib >> b) & 1u) ? __builtin_exp2f(e) * inv_s : 0.f;
    }
    adst[it * 256 + t] = o;
  }
}

// ---------------------------------------------------------------------------
// kpv: out0 = P @ h. r16 accounting: the LDS pipe was the floor (~1140
// cyc/iter/CU) because every wave read the whole 16 KB B tile per iter.
// Fix: 2x2 wave remap — wave (wr,wc) owns rows wr*32..+31 x cols wc*64..+63.
// B is read DIRECT from L2 (ht is L2-hot; 8 global b128/iter/wave, only its
// own 64-col half-slice -> no LDS-B, no double-buffer, NO per-iter barrier).
// A recomputed in-register from mask+f2s (exp2 x2 per wave — ~256 VALU cyc,
// far cheaper than the LDS traffic it replaces). Loop has zero stores, so
// B-loads issued at iter-top drain under the ~500-cyc afrag VALU chain.
// LDS: 4 KB f2s + 8.5 KB mask, staged once. grid: 1024 blocks, 256 threads
// ---------------------------------------------------------------------------
__global__ __launch_bounds__(256, 4) void kpv(const __bf16* __restrict__ ht,
                                              const float* __restrict__ f1,
                                              const float* __restrict__ f2,
                                              const float* __restrict__ sum,
                                              const u64* __restrict__ mask,
                                              float* __restrict__ out0) {
  __shared__ float f2s[KCHUNK];  // 4 KB
  __shared__ u64 ms[64][17];     // 8.5 KB (pad 17: spread row-groups)
  const int mb = blockIdx.x / KSPLIT;
  const int ks = blockIdx.x % KSPLIT;
  const int t    = threadIdx.x;
  const int w    = t >> 6;
  const int wr   = w >> 1;        // row half (0/1)
  const int wc   = w & 1;         // col half (0/1)
  const int lane = t & 63;
  const int lr = lane & 15;
  const int lc = lane >> 4;
  const int row0 = mb * 64;
  const int j0 = ks * KCHUNK;

  // ---- prologue: stage f2 chunk + mask chunk (once; no barrier in loop) ----
  {
    reinterpret_cast<f32x4*>(f2s)[t] =
        reinterpret_cast<const f32x4*>(f2 + j0)[t];
    const int r = t >> 2, q = (t & 3) * 4;
    const u64* msrc = mask + (size_t)(row0 + r) * 128 + (j0 >> 6) + q;
    ms[r][q]     = msrc[0];
    ms[r][q + 1] = msrc[1];
    ms[r][q + 2] = msrc[2];
    ms[r][q + 3] = msrc[3];
  }
  __syncthreads();

  const float f1r0 = f1[row0 + wr * 32 + lr];
  const float f1r1 = f1[row0 + wr * 32 + 16 + lr];
  // B base: this wave's 64-col slice, k from j0
  const __bf16* hbase =
      ht + (size_t)(wc * 64 + lr) * NROW + j0 + lc * 8;

  f32x4 acc[2][4];
  #pragma unroll
  for (int rt = 0; rt < 2; ++rt)
    #pragma unroll
    for (int n = 0; n < 4; ++n) acc[rt][n] = (f32x4){0.f, 0.f, 0.f, 0.f};

  for (int it = 0; it < NIT; ++it) {
    const int kk = it * 64;

    // ---- issue B loads first (L2 hits; only vmcnt ops in the loop) ----
    bf16x8 b[4][2];
    #pragma unroll
    for (int n = 0; n < 4; ++n) {
      const __bf16* hb = hbase + (size_t)(n * 16) * NROW + kk;
      b[n][0] = *reinterpret_cast<const bf16x8*>(hb);
      b[n][1] = *reinterpret_cast<const bf16x8*>(hb + 32);
    }

    // ---- A-fragments from mask + f2s (covered VALU; hides B latency) ----
    const u64 mw0 = ms[wr * 32 + lr][it];
    const u64 mw1 = ms[wr * 32 + 16 + lr][it];
    bf16x8 afrag[2][2];
    #pragma unroll
    for (int h = 0; h < 2; ++h) {
      const int base = kk + h * 32 + lc * 8;
      const f32x4 fa = *reinterpret_cast<const f32x4*>(&f2s[base]);
      const f32x4 fb = *reinterpret_cast<const f32x4*>(&f2s[base + 4]);
      const unsigned bits0 = (unsigned)(mw0 >> (h * 32 + lc * 8)) & 0xFFu;
      const unsigned bits1 = (unsigned)(mw1 >> (h * 32 + lc * 8)) & 0xFFu;
      #pragma unroll
      for (int i2 = 0; i2 < 8; ++i2) {
        const float fval = (i2 < 4) ? fa[i2] : fb[i2 - 4];
        float e0 = f1r0 + fval;
        e0 = e0 > 0.f ? e0 : 0.01f * e0;
        afrag[0][h][i2] =
            (__bf16)(((bits0 >> i2) & 1u) ? __builtin_exp2f(e0) : 0.f);
        float e1 = f1r1 + fval;
        e1 = e1 > 0.f ? e1 : 0.01f * e1;
        afrag[1][h][i2] =
            (__bf16)(((bits1 >> i2) & 1u) ? __builtin_exp2f(e1) : 0.f);
      }
    }

    // ---- MFMA: 2 row-tiles x 4 col-tiles x 2 k-halves ----
    #pragma unroll
    for (int rt = 0; rt < 2; ++rt)
      #pragma unroll
      for (int n = 0; n < 4; ++n) {
        acc[rt][n] = __builtin_amdgcn_mfma_f32_16x16x32_bf16(
            afrag[rt][0], b[n][0], acc[rt][n], 0, 0, 0);
        acc[rt][n] = __builtin_amdgcn_mfma_f32_16x16x32_bf16(
            afrag[rt][1], b[n][1], acc[rt][n], 0, 0, 0);
      }
  }

  // ---- epilogue: scale by 1/s, atomic accumulate ----
  #pragma unroll
  for (int rt = 0; rt < 2; ++rt) {
    float inv_sD[4];
    #pragma unroll
    for (int i2 = 0; i2 < 4; ++i2)
      inv_sD[i2] = 1.0f / sum[row0 + wr * 32 + rt * 16 + lc * 4 + i2];
    #pragma unroll
    for (int n = 0; n < 4; ++n) {
      #pragma unroll
      for (int i2 = 0; i2 < 4; ++i2) {
        atomicAdd(&out0[(size_t)(row0 + wr * 32 + rt * 16 + lc * 4 + i2) * OUTF +
                        wc * 64 + n * 16 + lr],
                  acc[rt][n][i2] * inv_sD[i2]);
      }
    }
  }
}

// ---------------------------------------------------------------------------
extern "C" void kernel_launch(void* const* d_in, const int* in_sizes, int n_in,
                              void* d_out, int out_size, void* d_ws, size_t ws_size,
                              hipStream_t stream) {
  const float* x   = (const float*)d_in[0];
  const int*   adj = (const int*)d_in[1];
  const float* W   = (const float*)d_in[2];
  const float* a   = (const float*)d_in[3];

  float* out0 = (float*)d_out;                       // 8192 x 128
  float* att  = (float*)d_out + (size_t)NROW * OUTF; // 8192 x 8192

  char* ws = (char*)d_ws;
  __bf16* ht = (__bf16*)ws;                                         // 2 MB
  u64* mask = (u64*)(ws + (2 << 20));                               // 8 MB
  float* f1 = (float*)(ws + (10 << 20));
  float* f2 = (float*)(ws + (10 << 20) + 32 * 1024);
  float* s  = (float*)(ws + (10 << 20) + 64 * 1024);

  hipMemsetAsync(out0, 0, (size_t)NROW * OUTF * sizeof(float), stream);
  k1<<<NROW / 32, 256, 0, stream>>>(x, W, a, ht, f1, f2);
  katt2<<<NROW, 256, 0, stream>>>(adj, f1, f2, mask, s, att);
  kpv<<<(NROW / 64) * KSPLIT, 256, 0, stream>>>(ht, f1, f2, s, mask, out0);
}